// Round 11
// baseline (140.549 us; speedup 1.0000x reference)
//
#include <hip/hip_runtime.h>
#include <hip/hip_bf16.h>

typedef __attribute__((ext_vector_type(4))) float  f32x4;
typedef __attribute__((ext_vector_type(8))) short  s16x8;
typedef __attribute__((ext_vector_type(4))) unsigned short u16x4;

#define D_MODEL 2048
#define NATOMS  64
#define RANK    6
#define NLAYERS 16
#define NAR     384
#define M_TOTAL 16384

#define AFSZ 1280      /* shorts per A buf: 32 x 40 (+8 pad) */
#define WFSZ 12288     /* shorts per W buf: 384 x 32 (linear) */
#define PSTR 392       /* Pl row stride in shorts */
#define BTSZ 12288     /* shorts per Bt buf: 64 x 192 (linear) */

static __device__ __forceinline__ unsigned short f2bf(float x){
    union { float f; unsigned u; } v; v.f = x;
    unsigned r = (v.u + 0x7FFF + ((v.u >> 16) & 1)) >> 16;
    return (unsigned short)r;
}

static __device__ __forceinline__ void gload_lds16(const void* g, void* l) {
    __builtin_amdgcn_global_load_lds(
        (const __attribute__((address_space(1))) unsigned int*)g,
        (__attribute__((address_space(3))) unsigned int*)l, 16, 0, 0);
}

static __device__ __forceinline__ u16x4 cvt4(f32x4 v) {
    u16x4 w;
    w.x = f2bf(v.x); w.y = f2bf(v.y); w.z = f2bf(v.z); w.w = f2bf(v.w);
    return w;
}

// ---------------------------------------------------------------------------
// Prep: gather layer slice, cast to bf16, lay out K-contiguous.
//   WbfT[n][d]  (n = a*6+r)   from A[a, l, d, r]
//   BbfT[p][n]                from B[a, l, r, p]
// ---------------------------------------------------------------------------
__global__ void prep_kernel(const float* __restrict__ A,
                            const float* __restrict__ B,
                            const int*   __restrict__ layer_idx,
                            unsigned short* __restrict__ WbfT,
                            unsigned short* __restrict__ BbfT)
{
    const int l = layer_idx[0];
    int idx = blockIdx.x * 256 + threadIdx.x;
    const int total = NAR * D_MODEL;   // 786432
    if (idx < total) {
        int n = idx / D_MODEL, d = idx % D_MODEL;
        int a = n / RANK, r = n % RANK;
        float v = A[((size_t)(a*NLAYERS + l) * D_MODEL + d) * RANK + r];
        WbfT[idx] = f2bf(v);
    } else {
        idx -= total;
        int p = idx / NAR, n = idx % NAR;
        int a = n / RANK, r = n % RANK;
        float v = B[((size_t)(a*NLAYERS + l) * RANK + r) * D_MODEL + p];
        BbfT[idx] = f2bf(v);
    }
}

// ---------------------------------------------------------------------------
// Fused LoRA, 2 blocks/CU (512 blocks x 256 threads, LDS 74240 B):
//   Phase 1: P[32][384] = scale*(hidden[32 rows] @ W^T), acc in regs.
//            BK=32; W dbuf gload_lds (XOR key (r>>1)&3); A reg-staged dbuf;
//            plain __syncthreads (co-resident block fills drains).
//   Phase 2: out[32][2048] = P @ B^T.  pf[2][12] pinned in regs (asm
//            keep-alive).  B staged in half-K slices of 64-col tiles
//            (24 KB each, dbuf, XOR key rB&7), ZERO read duplication
//            (4 waves x 16 cols, each wave all 32 P rows).
// ---------------------------------------------------------------------------
__global__ __launch_bounds__(256, 2) void fused_lora(
    const float*          __restrict__ hidden,  // [16384][2048] fp32
    const float*          __restrict__ scales,  // [4][64]
    const unsigned short* __restrict__ WbfT,    // [384][2048] bf16
    const unsigned short* __restrict__ BbfT,    // [2048][384] bf16
    float*                __restrict__ out)     // [16384][2048] fp32
{
    __shared__ __align__(16) char smem[74240];
    unsigned short* Af = (unsigned short*)smem;              // 2*AFSZ (5120 B)
    unsigned short* Wf = (unsigned short*)(smem + 5120);     // 2*WFSZ (49152 B)
    unsigned short* Pl = (unsigned short*)smem;              // 32x392 (25088 B)
    unsigned short* Bt = (unsigned short*)(smem + 25088);    // 2*BTSZ (49152 B)

    const int m0   = blockIdx.x * 32;
    const int tid  = threadIdx.x;
    const int lane = tid & 63;
    const int w    = tid >> 6;          // 0..3
    const int kq   = lane >> 4;         // 0..3 (k-quarter)

    // ---- phase 1 setup ----
    const int rowA = tid >> 3;          // 0..31
    const int cA   = (tid & 7) * 4;     // float col 0..28
    const float* srcA = hidden + (size_t)(m0 + rowA) * D_MODEL + cA;

    // W staging: 24 gload_lds of 4KB-block-share; wave w issues insts i=w*6+j.
    // chunk g = i*64+lane -> LDS row r=g>>2, chunk c=g&3 (16B).
    // Source pre-swizzled with key (r>>1)&3 (64B rows: spreads 16-row reads
    // across all 32 banks at 2-way).
    const unsigned short* srcW[6];
    int ldsW[6];
    #pragma unroll
    for (int j = 0; j < 6; ++j) {
        int i = w * 6 + j;
        int g = i * 64 + lane;
        int r = g >> 2, c = g & 3;
        srcW[j] = WbfT + (size_t)r * D_MODEL + (c ^ ((r >> 1) & 3)) * 8;
        ldsW[j] = i * 512;   // shorts
    }

    f32x4 acc[2][6] = {};
    f32x4 g;

    // ---- phase 1 prologue: stage tile 0 ----
    g = *reinterpret_cast<const f32x4*>(srcA); srcA += 32;
    *reinterpret_cast<u16x4*>(&Af[rowA * 40 + cA]) = cvt4(g);
    #pragma unroll
    for (int j = 0; j < 6; ++j) { gload_lds16(srcW[j], &Wf[ldsW[j]]); srcW[j] += 32; }
    __syncthreads();

    // ---- phase 1 main loop: 64 K-steps of 32 ----
    for (int t = 0; t < 64; ++t) {
        const int buf = t & 1;
        if (t < 63) {
            #pragma unroll
            for (int j = 0; j < 6; ++j) {
                gload_lds16(srcW[j], &Wf[(buf ^ 1) * WFSZ + ldsW[j]]);
                srcW[j] += 32;
            }
            g = *reinterpret_cast<const f32x4*>(srcA); srcA += 32;
        }
        const unsigned short* Ar = &Af[buf * AFSZ];
        const unsigned short* Wr = &Wf[buf * WFSZ];
        s16x8 bfr[6], afr[2];
        #pragma unroll
        for (int ni = 0; ni < 6; ++ni) {
            int br = w * 96 + ni * 16 + (lane & 15);
            bfr[ni] = *reinterpret_cast<const s16x8*>(
                &Wr[br * 32 + ((kq ^ ((br >> 1) & 3)) << 3)]);
        }
        #pragma unroll
        for (int mi = 0; mi < 2; ++mi)
            afr[mi] = *reinterpret_cast<const s16x8*>(
                &Ar[(mi * 16 + (lane & 15)) * 40 + kq * 8]);
        #pragma unroll
        for (int mi = 0; mi < 2; ++mi)
            #pragma unroll
            for (int ni = 0; ni < 6; ++ni)
                acc[mi][ni] = __builtin_amdgcn_mfma_f32_16x16x32_bf16(
                    afr[mi], bfr[ni], acc[mi][ni], 0, 0, 0);
        if (t < 63) {
            *reinterpret_cast<u16x4*>(&Af[(buf ^ 1) * AFSZ + rowA * 40 + cA]) = cvt4(g);
            __syncthreads();
        }
    }
    __syncthreads();   // all Wf/Af reads done; safe to overwrite with Pl

    // ---- transition: scale + cvt acc -> Pl ----
    const int b = m0 >> 12;
    #pragma unroll
    for (int ni = 0; ni < 6; ++ni) {
        int col  = w * 96 + ni * 16 + (lane & 15);
        float sc = scales[b * NATOMS + col / RANK];
        #pragma unroll
        for (int mi = 0; mi < 2; ++mi) {
            #pragma unroll
            for (int r = 0; r < 4; ++r) {
                int row = mi * 16 + kq * 4 + r;
                Pl[row * PSTR + col] = f2bf(acc[mi][ni][r] * sc);
            }
        }
    }
    __syncthreads();

    // ---- phase 2 setup ----
    // pf: all 32 P rows x 384 k per wave, pinned in registers.
    s16x8 pf[2][12];
    #pragma unroll
    for (int mi = 0; mi < 2; ++mi)
        #pragma unroll
        for (int ks = 0; ks < 12; ++ks) {
            pf[mi][ks] = *reinterpret_cast<const s16x8*>(
                &Pl[(mi * 16 + (lane & 15)) * PSTR + (ks * 4 + kq) * 8]);
            asm volatile("" : "+v"(pf[mi][ks]));   // pin: barriers can't force re-read
        }

    // Bt staging: half-K slice (64 rows x 192 shorts = 24KB), 24 gload_lds.
    // chunk g = (w*6+j)*64+lane -> row rr=g/24, chunk cc=g%24; source
    // pre-swizzled with key rr&7.
    const unsigned short* srcB[6];
    int ldsB[6];
    #pragma unroll
    for (int j = 0; j < 6; ++j) {
        int gi = (w * 6 + j) * 64 + lane;
        int rr = gi / 24, cc = gi % 24;
        srcB[j] = BbfT + (size_t)rr * NAR + (cc ^ (rr & 7)) * 8;
        ldsB[j] = (w * 6 + j) * 512;
    }
    const int rB = w * 16 + (lane & 15);   // out-col within tile (= B row)

    // prologue: stage (tile 0, half 0) into Bt[0]
    #pragma unroll
    for (int j = 0; j < 6; ++j) gload_lds16(srcB[j], &Bt[ldsB[j]]);
    __syncthreads();

    // ---- phase 2 main loop: 32 tiles x 2 k-halves, dbuf ----
    for (int tl = 0; tl < 32; ++tl) {
        f32x4 a2[2] = {};
        // half 0 (reads Bt[0]); stage (tl, h1) -> Bt[1]
        {
            #pragma unroll
            for (int j = 0; j < 6; ++j)
                gload_lds16(srcB[j] + (size_t)tl * 64 * NAR + 192, &Bt[BTSZ + ldsB[j]]);
            #pragma unroll
            for (int ks = 0; ks < 6; ++ks) {
                s16x8 bfr = *reinterpret_cast<const s16x8*>(
                    &Bt[rB * 192 + (((ks * 4 + kq) ^ (rB & 7)) << 3)]);
                #pragma unroll
                for (int mi = 0; mi < 2; ++mi)
                    a2[mi] = __builtin_amdgcn_mfma_f32_16x16x32_bf16(
                        pf[mi][ks], bfr, a2[mi], 0, 0, 0);
            }
            __syncthreads();
        }
        // half 1 (reads Bt[1]); stage (tl+1, h0) -> Bt[0]; store
        {
            if (tl < 31) {
                #pragma unroll
                for (int j = 0; j < 6; ++j)
                    gload_lds16(srcB[j] + (size_t)(tl + 1) * 64 * NAR, &Bt[ldsB[j]]);
            }
            #pragma unroll
            for (int ks = 0; ks < 6; ++ks) {
                s16x8 bfr = *reinterpret_cast<const s16x8*>(
                    &Bt[BTSZ + rB * 192 + (((ks * 4 + kq) ^ (rB & 7)) << 3)]);
                #pragma unroll
                for (int mi = 0; mi < 2; ++mi)
                    a2[mi] = __builtin_amdgcn_mfma_f32_16x16x32_bf16(
                        pf[mi][6 + ks], bfr, a2[mi], 0, 0, 0);
            }
            #pragma unroll
            for (int mi = 0; mi < 2; ++mi) {
                #pragma unroll
                for (int r = 0; r < 4; ++r) {
                    int row = m0 + mi * 16 + kq * 4 + r;
                    int col = tl * 64 + rB;
                    out[(size_t)row * D_MODEL + col] = a2[mi][r];
                }
            }
            if (tl < 31) __syncthreads();
        }
    }
}

extern "C" void kernel_launch(void* const* d_in, const int* in_sizes, int n_in,
                              void* d_out, int out_size, void* d_ws, size_t ws_size,
                              hipStream_t stream)
{
    const float* hidden    = (const float*)d_in[0];
    const float* scales    = (const float*)d_in[1];
    const float* A         = (const float*)d_in[2];
    const float* B         = (const float*)d_in[3];
    const int*   layer_idx = (const int*)d_in[4];
    float* out = (float*)d_out;

    unsigned short* WbfT = (unsigned short*)d_ws;            // [384][2048]
    unsigned short* BbfT = WbfT + (size_t)NAR * D_MODEL;     // [2048][384]

    prep_kernel<<<(2 * NAR * D_MODEL) / 256, 256, 0, stream>>>(A, B, layer_idx, WbfT, BbfT);
    fused_lora<<<M_TOTAL / 32, 256, 0, stream>>>(hidden, scales, WbfT, BbfT, out);
}

// Round 12
// 90.645 us; speedup vs baseline: 1.5505x; 1.5505x over previous
//
#include <hip/hip_runtime.h>
#include <hip/hip_bf16.h>

typedef __attribute__((ext_vector_type(4))) float  f32x4;
typedef __attribute__((ext_vector_type(8))) short  s16x8;

#define D_MODEL 2048
#define NATOMS  64
#define RANK    6
#define NLAYERS 16
#define NAR     384
#define M_TOTAL 16384

#define ASZ  (64*72)    /* shorts: A buffer (+8 pad) */
#define WSZ  (384*64)   /* shorts: W buffer (linear, gload_lds) */
#define PSTR 392        /* P_lds row stride in shorts */
#define BSZ  (64*384)   /* shorts: one Bt buffer (linear, gload_lds) */

static __device__ __forceinline__ unsigned short f2bf(float x){
    union { float f; unsigned u; } v; v.f = x;
    unsigned r = (v.u + 0x7FFF + ((v.u >> 16) & 1)) >> 16;
    return (unsigned short)r;
}

static __device__ __forceinline__ void gload_lds16(const void* g, void* l) {
    __builtin_amdgcn_global_load_lds(
        (const __attribute__((address_space(1))) unsigned int*)g,
        (__attribute__((address_space(3))) unsigned int*)l, 16, 0, 0);
}

static __device__ __forceinline__ s16x8 cvt8(f32x4 lo, f32x4 hi) {
    union { s16x8 v; unsigned short s[8]; } u;
    u.s[0] = f2bf(lo.x); u.s[1] = f2bf(lo.y); u.s[2] = f2bf(lo.z); u.s[3] = f2bf(lo.w);
    u.s[4] = f2bf(hi.x); u.s[5] = f2bf(hi.y); u.s[6] = f2bf(hi.z); u.s[7] = f2bf(hi.w);
    return u.v;
}

// ---------------------------------------------------------------------------
// Prep: gather layer slice, cast to bf16, lay out K-contiguous.
//   WbfT[n][d]  (n = a*6+r)   from A[a, l, d, r]
//   BbfT[p][n]                from B[a, l, r, p]
// ---------------------------------------------------------------------------
__global__ void prep_kernel(const float* __restrict__ A,
                            const float* __restrict__ B,
                            const int*   __restrict__ layer_idx,
                            unsigned short* __restrict__ WbfT,
                            unsigned short* __restrict__ BbfT)
{
    const int l = layer_idx[0];
    int idx = blockIdx.x * 256 + threadIdx.x;
    const int total = NAR * D_MODEL;   // 786432
    if (idx < total) {
        int n = idx / D_MODEL, d = idx % D_MODEL;
        int a = n / RANK, r = n % RANK;
        float v = A[((size_t)(a*NLAYERS + l) * D_MODEL + d) * RANK + r];
        WbfT[idx] = f2bf(v);
    } else {
        idx -= total;
        int p = idx / NAR, n = idx % NAR;
        int a = n / RANK, r = n % RANK;
        float v = B[((size_t)(a*NLAYERS + l) * RANK + r) * D_MODEL + p];
        BbfT[idx] = f2bf(v);
    }
}

// ---------------------------------------------------------------------------
// Fused LoRA (256 blocks = 1/CU, 512 threads = 8 waves) — R10 structure.
//   Phase 1: P[64][384] = scale*(hidden @ W^T) in regs; W dbuf gload_lds +
//            XOR swizzle; A reg-staged; counted vmcnt(2) barriers.
//   Phase 2: out[64][2048] = P @ B^T.  pf[2][12] loaded ONCE via inline-asm
//            ds_read_b128 (non-rematerializable -> genuinely register-
//            resident across all 32 tiles).  B staged per 64-col tile via
//            gload_lds dbuf (XOR-preswizzled source).  Tile barrier =
//            s_waitcnt vmcnt(8) + s_barrier (stores stay in flight).
// ---------------------------------------------------------------------------
__global__ __launch_bounds__(512, 1) void fused_lora(
    const float*          __restrict__ hidden,  // [16384][2048] fp32
    const float*          __restrict__ scales,  // [4][64]
    const unsigned short* __restrict__ WbfT,    // [384][2048] bf16
    const unsigned short* __restrict__ BbfT,    // [2048][384] bf16
    float*                __restrict__ out)     // [16384][2048] fp32
{
    __shared__ __align__(16) char smem[148480];
    unsigned short* Af = (unsigned short*)smem;            // 2*ASZ  (18432 B)
    unsigned short* Wf = (unsigned short*)(smem + 18432);  // 2*WSZ  (98304 B)
    unsigned short* Pl = (unsigned short*)smem;            // 64x392 (50176 B) @ LDS off 0
    unsigned short* Bt = (unsigned short*)(smem + 50176);  // 2*BSZ  (98304 B)

    const int m0   = blockIdx.x * 64;
    const int tid  = threadIdx.x;
    const int lane = tid & 63;
    const int w    = tid >> 6;          // 0..7
    const int wr   = w >> 2, wc = w & 3;   // phase1: rows wr*32, cols wc*96
    const int kq   = lane >> 4;         // 0..3

    // ---- phase 1 setup ----
    const int rowA = tid >> 3;          // 0..63
    const int c8A  = tid & 7;           // 0..7
    const float* srcA = hidden + (size_t)(m0 + rowA) * D_MODEL + c8A * 8;

    // W staging: 48 gload_lds of 1KB; wave w does insts i = w*6+j.
    const unsigned short* srcW[6];
    int ldsW[6];
    #pragma unroll
    for (int j = 0; j < 6; ++j) {
        int i = w * 6 + j;
        int r = i * 8 + (lane >> 3);
        int c = (lane & 7) ^ (r & 7);
        srcW[j] = WbfT + (size_t)r * D_MODEL + c * 8;
        ldsW[j] = i * 512;   // shorts
    }

    f32x4 acc[2][6] = {};
    f32x4 ga[2], gb[2];

    // ---- phase 1 prologue ----
    ga[0] = *reinterpret_cast<const f32x4*>(srcA);
    ga[1] = *reinterpret_cast<const f32x4*>(srcA + 4);
    srcA += 64;
    {
        s16x8 s = cvt8(ga[0], ga[1]);
        *reinterpret_cast<s16x8*>(&Af[rowA * 72 + c8A * 8]) = s;
    }
    #pragma unroll
    for (int j = 0; j < 6; ++j) { gload_lds16(srcW[j], &Wf[ldsW[j]]); srcW[j] += 64; }
    __builtin_amdgcn_sched_barrier(0);
    gb[0] = *reinterpret_cast<const f32x4*>(srcA);          // A(1)
    gb[1] = *reinterpret_cast<const f32x4*>(srcA + 4);
    srcA += 64;
    asm volatile("s_waitcnt vmcnt(2) lgkmcnt(0)" ::: "memory");  // W(0) done, A(1) in flight
    __builtin_amdgcn_s_barrier();

    // ---- phase 1 main loop ----
    auto body = [&](int t, f32x4 (&gI)[2], f32x4 (&gC)[2]) {
        const int buf = t & 1;
        if (t < 31) {
            #pragma unroll
            for (int j = 0; j < 6; ++j) {
                gload_lds16(srcW[j], &Wf[(buf ^ 1) * WSZ + ldsW[j]]);
                srcW[j] += 64;
            }
        }
        __builtin_amdgcn_sched_barrier(0);   // pin: W gloads before A loads
        if (t < 30) {
            gI[0] = *reinterpret_cast<const f32x4*>(srcA);
            gI[1] = *reinterpret_cast<const f32x4*>(srcA + 4);
            srcA += 64;
        }
        const unsigned short* Ar = &Af[buf * ASZ];
        const unsigned short* Wr = &Wf[buf * WSZ];
        #pragma unroll
        for (int kk = 0; kk < 2; ++kk) {
            const int kch = kk * 4 + kq;
            s16x8 bfr[6], afr[2];
            #pragma unroll
            for (int ni = 0; ni < 6; ++ni) {
                int br = wc * 96 + ni * 16 + (lane & 15);
                bfr[ni] = *reinterpret_cast<const s16x8*>(
                    &Wr[br * 64 + ((kch ^ (br & 7)) << 3)]);
            }
            #pragma unroll
            for (int mi = 0; mi < 2; ++mi) {
                int ar = wr * 32 + mi * 16 + (lane & 15);
                afr[mi] = *reinterpret_cast<const s16x8*>(
                    &Ar[ar * 72 + kk * 32 + kq * 8]);
            }
            #pragma unroll
            for (int mi = 0; mi < 2; ++mi)
                #pragma unroll
                for (int ni = 0; ni < 6; ++ni)
                    acc[mi][ni] = __builtin_amdgcn_mfma_f32_16x16x32_bf16(
                        afr[mi], bfr[ni], acc[mi][ni], 0, 0, 0);
        }
        if (t < 31) {
            s16x8 s = cvt8(gC[0], gC[1]);
            *reinterpret_cast<s16x8*>(&Af[(buf ^ 1) * ASZ + rowA * 72 + c8A * 8]) = s;
            if (t == 30) asm volatile("s_waitcnt vmcnt(0) lgkmcnt(0)" ::: "memory");
            else         asm volatile("s_waitcnt vmcnt(2) lgkmcnt(0)" ::: "memory");
            __builtin_amdgcn_s_barrier();
        }
    };
    for (int tt = 0; tt < 32; tt += 2) {
        body(tt,     ga, gb);
        body(tt + 1, gb, ga);
    }
    __syncthreads();   // phase-1 LDS reads complete; safe to overwrite with P

    // ---- transition: scale + cvt acc -> P_lds ----
    const int b = m0 >> 12;
    #pragma unroll
    for (int ni = 0; ni < 6; ++ni) {
        int col  = wc * 96 + ni * 16 + (lane & 15);
        float sc = scales[b * NATOMS + col / RANK];
        #pragma unroll
        for (int mi = 0; mi < 2; ++mi) {
            #pragma unroll
            for (int r = 0; r < 4; ++r) {
                int row = wr * 32 + mi * 16 + kq * 4 + r;
                Pl[row * PSTR + col] = f2bf(acc[mi][ni][r] * sc);
            }
        }
    }
    __syncthreads();

    // ---- phase 2 setup ----
    const int wr2 = w >> 2, wp = w & 3;   // out rows wr2*32, cols pt*64 + wp*16

    // P fragments -> registers ONCE via inline-asm ds_read_b128:
    // asm-produced values cannot be rematerialized from LDS -> genuinely
    // resident for all 32 tiles (R10's compiler re-read them every tile).
    // Pl sits at LDS byte offset 0, so smem-offset == ds address.
    s16x8 pf[2][12];
    #pragma unroll
    for (int mi = 0; mi < 2; ++mi)
        #pragma unroll
        for (int ks = 0; ks < 12; ++ks) {
            unsigned boff = (unsigned)(((wr2 * 32 + mi * 16 + (lane & 15)) * PSTR
                                        + (ks * 4 + kq) * 8) * 2);
            asm volatile("ds_read_b128 %0, %1" : "=v"(pf[mi][ks]) : "v"(boff));
        }
    asm volatile("s_waitcnt lgkmcnt(0)" ::: "memory");
    __builtin_amdgcn_sched_barrier(0);   // rule #18: fence MFMA hoisting

    // Bt staging: 64 rows x 384 shorts = 3072 chunks of 16B; 6 gload_lds of
    // 8KB each.  Source pre-swizzled: LDS chunk c of row r holds global
    // chunk c^(r&7) -> read applies same XOR (involution).
    const unsigned short* srcB[6];
    int dstB[6];
    #pragma unroll
    for (int j = 0; j < 6; ++j) {
        int g  = j * 512 + tid;
        int rB = g / 48, cB = g % 48;
        srcB[j] = BbfT + (size_t)rB * NAR + (cB ^ (rB & 7)) * 8;
        dstB[j] = g * 8;   // linear LDS short offset
    }
    const int rowB = wp * 16 + (lane & 15);

    // prologue: stage Bt(0)
    #pragma unroll
    for (int j = 0; j < 6; ++j) gload_lds16(srcB[j], &Bt[dstB[j]]);
    asm volatile("s_waitcnt vmcnt(0)" ::: "memory");
    __builtin_amdgcn_s_barrier();

    // ---- phase 2 main loop: 32 p-tiles of 64 cols ----
    for (int pt = 0; pt < 32; ++pt) {
        const int buf = pt & 1;
        // 1. issue Bt(pt+1) gloads (oldest VMEM ops this tile)
        if (pt < 31) {
            #pragma unroll
            for (int j = 0; j < 6; ++j)
                gload_lds16(srcB[j] + (size_t)(pt + 1) * 64 * NAR,
                            &Bt[(buf ^ 1) * BSZ + dstB[j]]);
        }
        __builtin_amdgcn_sched_barrier(0);
        // 2. compute tile pt from Bt[buf] + register-resident pf
        f32x4 a2[2] = {};
        const unsigned short* Br = &Bt[buf * BSZ];
        #pragma unroll
        for (int ks = 0; ks < 12; ++ks) {
            s16x8 bfr = *reinterpret_cast<const s16x8*>(
                &Br[(rowB * 48 + ((ks * 4 + kq) ^ (rowB & 7))) * 8]);
            #pragma unroll
            for (int mi = 0; mi < 2; ++mi)
                a2[mi] = __builtin_amdgcn_mfma_f32_16x16x32_bf16(
                    pf[mi][ks], bfr, a2[mi], 0, 0, 0);
        }
        // 3. store tile pt
        #pragma unroll
        for (int mi = 0; mi < 2; ++mi) {
            #pragma unroll
            for (int r = 0; r < 4; ++r) {
                int row = m0 + wr2 * 32 + mi * 16 + kq * 4 + r;
                int col = pt * 64 + wp * 16 + (lane & 15);
                out[(size_t)row * D_MODEL + col] = a2[mi][r];
            }
        }
        // 4. barrier: gloads (6 oldest) drained; this tile's stores in flight
        if (pt < 31) {
            asm volatile("s_waitcnt vmcnt(8)" ::: "memory");
            __builtin_amdgcn_s_barrier();
        }
    }
}

extern "C" void kernel_launch(void* const* d_in, const int* in_sizes, int n_in,
                              void* d_out, int out_size, void* d_ws, size_t ws_size,
                              hipStream_t stream)
{
    const float* hidden    = (const float*)d_in[0];
    const float* scales    = (const float*)d_in[1];
    const float* A         = (const float*)d_in[2];
    const float* B         = (const float*)d_in[3];
    const int*   layer_idx = (const int*)d_in[4];
    float* out = (float*)d_out;

    unsigned short* WbfT = (unsigned short*)d_ws;            // [384][2048]
    unsigned short* BbfT = WbfT + (size_t)NAR * D_MODEL;     // [2048][384]

    prep_kernel<<<(2 * NAR * D_MODEL) / 256, 256, 0, stream>>>(A, B, layer_idx, WbfT, BbfT);
    fused_lora<<<M_TOTAL / 64, 512, 0, stream>>>(hidden, scales, WbfT, BbfT, out);
}